// Round 2
// baseline (3896.600 us; speedup 1.0000x reference)
//
#include <hip/hip_runtime.h>
#include <math.h>

// Problem constants
#define Bv 128
#define Pv 196
#define Ev 512
#define Hv 512
#define Vv 12000
#define Tv 20

__device__ __forceinline__ float sigf(float x) { return 1.0f / (1.0f + __expf(-x)); }

// ---------------------------------------------------------------------------
// K0: att1[m, a] = sum_e enc[m, e] * We[a, e] + be[a]
// M = B*P = 25088, N = 512, K = 512.  MT=128, NT=64, KT=16, 256 thr, 8x4/thread
// ---------------------------------------------------------------------------
__global__ __launch_bounds__(256) void k_att1(const float* __restrict__ A,
                                              const float* __restrict__ Bw,
                                              const float* __restrict__ bias,
                                              float* __restrict__ C) {
    __shared__ __align__(16) float As[16][128];
    __shared__ __align__(16) float Bs[16][68];
    const int m0 = blockIdx.x * 128;
    const int n0 = blockIdx.y * 64;
    const int tid = threadIdx.x;
    const int ng = tid & 15, mg = tid >> 4;
    float acc[8][4];
#pragma unroll
    for (int i = 0; i < 8; i++)
#pragma unroll
        for (int j = 0; j < 4; j++) acc[i][j] = 0.f;

    for (int k0 = 0; k0 < 512; k0 += 16) {
#pragma unroll
        for (int q = 0; q < 2; q++) {
            int f = tid * 2 + q;
            int m = f >> 2, kc = (f & 3) * 4;
            float4 v = *(const float4*)&A[(size_t)(m0 + m) * 512 + k0 + kc];
            As[kc + 0][m] = v.x; As[kc + 1][m] = v.y; As[kc + 2][m] = v.z; As[kc + 3][m] = v.w;
        }
        {
            int n = tid >> 2, kc = (tid & 3) * 4;
            float4 v = *(const float4*)&Bw[(size_t)(n0 + n) * 512 + k0 + kc];
            Bs[kc + 0][n] = v.x; Bs[kc + 1][n] = v.y; Bs[kc + 2][n] = v.z; Bs[kc + 3][n] = v.w;
        }
        __syncthreads();
#pragma unroll
        for (int kk = 0; kk < 16; kk++) {
            float4 a0 = *(const float4*)&As[kk][mg * 8];
            float4 a1 = *(const float4*)&As[kk][mg * 8 + 4];
            float4 b  = *(const float4*)&Bs[kk][ng * 4];
            float am[8] = {a0.x, a0.y, a0.z, a0.w, a1.x, a1.y, a1.z, a1.w};
            float bn[4] = {b.x, b.y, b.z, b.w};
#pragma unroll
            for (int i = 0; i < 8; i++)
#pragma unroll
                for (int j = 0; j < 4; j++) acc[i][j] = fmaf(am[i], bn[j], acc[i][j]);
        }
        __syncthreads();
    }
#pragma unroll
    for (int i = 0; i < 8; i++) {
        int m = m0 + mg * 8 + i;
#pragma unroll
        for (int j = 0; j < 4; j++) {
            int n = n0 + ng * 4 + j;
            C[(size_t)m * 512 + n] = acc[i][j] + bias[n];
        }
    }
}

// ---------------------------------------------------------------------------
// K2: per-b attention.  One block per b, 512 threads.
//   att2 = h @ Wd^T + bd   (per-thread row dot, Wd is L2-resident 1MB)
//   e[p] = sum_a Wf[a] * relu(att1[b,p,a] + att2[a])   (bf cancels in softmax)
//   alpha = softmax_p(e);  write alpha to d_out
//   ctx[e] = sum_p alpha[p] * enc[b,p,e]
// ---------------------------------------------------------------------------
__global__ __launch_bounds__(512) void k_attn(const float* __restrict__ att1,
                                              const float* __restrict__ enc,
                                              const float* __restrict__ h,
                                              const float* __restrict__ Wd,
                                              const float* __restrict__ bd,
                                              const float* __restrict__ Wf,
                                              float* __restrict__ ctx,
                                              float* __restrict__ alpha_out,
                                              int t) {
    __shared__ float h_s[512];
    __shared__ float att2_s[512];
    __shared__ float e_s[200];
    __shared__ float alpha_s[200];
    const int b = blockIdx.x;
    const int tid = threadIdx.x;

    h_s[tid] = h[b * 512 + tid];
    __syncthreads();

    // --- att2 ---
    {
        float acc = bd[tid];
        const float4* wrow = (const float4*)&Wd[(size_t)tid * 512];
        const float4* hv4 = (const float4*)h_s;
#pragma unroll 2
        for (int k4 = 0; k4 < 128; k4 += 8) {
            float4 w0 = wrow[k4 + 0], w1 = wrow[k4 + 1], w2 = wrow[k4 + 2], w3 = wrow[k4 + 3];
            float4 w4 = wrow[k4 + 4], w5 = wrow[k4 + 5], w6 = wrow[k4 + 6], w7 = wrow[k4 + 7];
            float4 x0 = hv4[k4 + 0], x1 = hv4[k4 + 1], x2 = hv4[k4 + 2], x3 = hv4[k4 + 3];
            float4 x4 = hv4[k4 + 4], x5 = hv4[k4 + 5], x6 = hv4[k4 + 6], x7 = hv4[k4 + 7];
            acc += w0.x * x0.x + w0.y * x0.y + w0.z * x0.z + w0.w * x0.w;
            acc += w1.x * x1.x + w1.y * x1.y + w1.z * x1.z + w1.w * x1.w;
            acc += w2.x * x2.x + w2.y * x2.y + w2.z * x2.z + w2.w * x2.w;
            acc += w3.x * x3.x + w3.y * x3.y + w3.z * x3.z + w3.w * x3.w;
            acc += w4.x * x4.x + w4.y * x4.y + w4.z * x4.z + w4.w * x4.w;
            acc += w5.x * x5.x + w5.y * x5.y + w5.z * x5.z + w5.w * x5.w;
            acc += w6.x * x6.x + w6.y * x6.y + w6.z * x6.z + w6.w * x6.w;
            acc += w7.x * x7.x + w7.y * x7.y + w7.z * x7.z + w7.w * x7.w;
        }
        att2_s[tid] = acc;
    }
    __syncthreads();

    // --- e ---
    const int lane = tid & 63;
    const int wv = tid >> 6;
    float att2r[8], wfr[8];
#pragma unroll
    for (int j = 0; j < 8; j++) {
        att2r[j] = att2_s[lane * 8 + j];
        wfr[j] = Wf[lane * 8 + j];
    }
    for (int p = wv; p < 196; p += 8) {
        const float4* a4 = (const float4*)&att1[((size_t)(b * 196 + p)) * 512 + lane * 8];
        float4 v0 = a4[0], v1 = a4[1];
        float s = 0.f;
        s += wfr[0] * fmaxf(v0.x + att2r[0], 0.f);
        s += wfr[1] * fmaxf(v0.y + att2r[1], 0.f);
        s += wfr[2] * fmaxf(v0.z + att2r[2], 0.f);
        s += wfr[3] * fmaxf(v0.w + att2r[3], 0.f);
        s += wfr[4] * fmaxf(v1.x + att2r[4], 0.f);
        s += wfr[5] * fmaxf(v1.y + att2r[5], 0.f);
        s += wfr[6] * fmaxf(v1.z + att2r[6], 0.f);
        s += wfr[7] * fmaxf(v1.w + att2r[7], 0.f);
#pragma unroll
        for (int off = 32; off; off >>= 1) s += __shfl_xor(s, off);
        if (lane == 0) e_s[p] = s;
    }
    __syncthreads();

    // --- softmax (wave 0) ---
    if (wv == 0) {
        float v0 = e_s[lane], v1 = e_s[lane + 64], v2 = e_s[lane + 128];
        float v3 = (lane < 4) ? e_s[lane + 192] : -1e30f;
        float mx = fmaxf(fmaxf(v0, v1), fmaxf(v2, v3));
#pragma unroll
        for (int off = 32; off; off >>= 1) mx = fmaxf(mx, __shfl_xor(mx, off));
        float x0 = __expf(v0 - mx), x1 = __expf(v1 - mx), x2 = __expf(v2 - mx);
        float x3 = (lane < 4) ? __expf(v3 - mx) : 0.f;
        float sm = x0 + x1 + x2 + x3;
#pragma unroll
        for (int off = 32; off; off >>= 1) sm += __shfl_xor(sm, off);
        float inv = 1.0f / sm;
        x0 *= inv; x1 *= inv; x2 *= inv; x3 *= inv;
        alpha_s[lane] = x0; alpha_s[lane + 64] = x1; alpha_s[lane + 128] = x2;
        if (lane < 4) alpha_s[lane + 192] = x3;
        float* ao = alpha_out + ((size_t)b * Tv + t) * 196;
        ao[lane] = x0; ao[lane + 64] = x1; ao[lane + 128] = x2;
        if (lane < 4) ao[lane + 192] = x3;
    }
    __syncthreads();

    // --- ctx ---
    {
        float acc = 0.f;
        const float* erow = &enc[(size_t)b * 196 * 512 + tid];
#pragma unroll 2
        for (int p = 0; p < 196; p += 4) {
            float e0 = erow[(size_t)(p + 0) * 512];
            float e1 = erow[(size_t)(p + 1) * 512];
            float e2 = erow[(size_t)(p + 2) * 512];
            float e3 = erow[(size_t)(p + 3) * 512];
            acc += alpha_s[p + 0] * e0 + alpha_s[p + 1] * e1 + alpha_s[p + 2] * e2 + alpha_s[p + 3] * e3;
        }
        ctx[b * 512 + tid] = acc;
    }
}

// ---------------------------------------------------------------------------
// K3: gates split-K GEMM.  gates[b, n] partials over virtual K=1536:
//   k<512: emb_table[cap[b]][k];  k<1024: ctx[b][k-512];  else h[b][k-1024]
//   B op:  k<1024: W_ih[n][k];    else W_hh[n][k-1024]
// grid (32 n-blocks, 8 k-splits), 256 thr, MT=128(all b) x NT=64, 8x4/thread
// writes parts[s][b][n] (no bias)
// ---------------------------------------------------------------------------
__global__ __launch_bounds__(256) void k_gates(const float* __restrict__ emb_table,
                                               const int* __restrict__ captions,
                                               const float* __restrict__ ctx,
                                               const float* __restrict__ h,
                                               const float* __restrict__ W_ih,
                                               const float* __restrict__ W_hh,
                                               float* __restrict__ parts,
                                               int t) {
    __shared__ __align__(16) float As[16][128];
    __shared__ __align__(16) float Bs[16][68];
    __shared__ int cap_s[128];
    const int n0 = blockIdx.x * 64;
    const int s = blockIdx.y;
    const int tid = threadIdx.x;
    if (tid < 128) cap_s[tid] = captions[tid * Tv + t];
    __syncthreads();

    const int ng = tid & 15, mg = tid >> 4;
    float acc[8][4];
#pragma unroll
    for (int i = 0; i < 8; i++)
#pragma unroll
        for (int j = 0; j < 4; j++) acc[i][j] = 0.f;

    const int kbase = s * 192;
    for (int kt = 0; kt < 192; kt += 16) {
        const int k0 = kbase + kt;
#pragma unroll
        for (int q = 0; q < 2; q++) {
            int f = tid * 2 + q;
            int m = f >> 2, kc = (f & 3) * 4;
            int k = k0 + kc;
            float4 v;
            if (k < 512)
                v = *(const float4*)&emb_table[(size_t)cap_s[m] * 512 + k];
            else if (k < 1024)
                v = *(const float4*)&ctx[m * 512 + (k - 512)];
            else
                v = *(const float4*)&h[m * 512 + (k - 1024)];
            As[kc + 0][m] = v.x; As[kc + 1][m] = v.y; As[kc + 2][m] = v.z; As[kc + 3][m] = v.w;
        }
        {
            int n = tid >> 2, kc = (tid & 3) * 4;
            int k = k0 + kc;
            float4 v;
            if (k < 1024)
                v = *(const float4*)&W_ih[(size_t)(n0 + n) * 1024 + k];
            else
                v = *(const float4*)&W_hh[(size_t)(n0 + n) * 512 + (k - 1024)];
            Bs[kc + 0][n] = v.x; Bs[kc + 1][n] = v.y; Bs[kc + 2][n] = v.z; Bs[kc + 3][n] = v.w;
        }
        __syncthreads();
#pragma unroll
        for (int kk = 0; kk < 16; kk++) {
            float4 a0 = *(const float4*)&As[kk][mg * 8];
            float4 a1 = *(const float4*)&As[kk][mg * 8 + 4];
            float4 b  = *(const float4*)&Bs[kk][ng * 4];
            float am[8] = {a0.x, a0.y, a0.z, a0.w, a1.x, a1.y, a1.z, a1.w};
            float bn[4] = {b.x, b.y, b.z, b.w};
#pragma unroll
            for (int i = 0; i < 8; i++)
#pragma unroll
                for (int j = 0; j < 4; j++) acc[i][j] = fmaf(am[i], bn[j], acc[i][j]);
        }
        __syncthreads();
    }
#pragma unroll
    for (int i = 0; i < 8; i++) {
        int m = mg * 8 + i;
#pragma unroll
        for (int j = 0; j < 4; j++) {
            parts[((size_t)s * 128 + m) * 2048 + n0 + ng * 4 + j] = acc[i][j];
        }
    }
}

// ---------------------------------------------------------------------------
// K4: LSTM pointwise + beta-gate GEMV + gh.  One block per b, 512 threads.
// ---------------------------------------------------------------------------
__global__ __launch_bounds__(512) void k_lstm(const float* __restrict__ parts,
                                              const float* __restrict__ b_ih,
                                              const float* __restrict__ b_hh,
                                              const float* __restrict__ Wb,
                                              const float* __restrict__ bb,
                                              float* __restrict__ h,
                                              float* __restrict__ c,
                                              float* __restrict__ gh) {
    __shared__ float h_s[512];
    const int b = blockIdx.x;
    const int j = threadIdx.x;
    float gi = b_ih[j] + b_hh[j];
    float gf = b_ih[j + 512] + b_hh[j + 512];
    float gg = b_ih[j + 1024] + b_hh[j + 1024];
    float go = b_ih[j + 1536] + b_hh[j + 1536];
#pragma unroll
    for (int s = 0; s < 8; s++) {
        const float* pr = &parts[((size_t)s * 128 + b) * 2048];
        gi += pr[j]; gf += pr[j + 512]; gg += pr[j + 1024]; go += pr[j + 1536];
    }
    float cn = sigf(gf) * c[b * 512 + j] + sigf(gi) * tanhf(gg);
    float hn = sigf(go) * tanhf(cn);
    c[b * 512 + j] = cn;
    h[b * 512 + j] = hn;
    h_s[j] = hn;
    __syncthreads();

    // beta gate
    float acc = bb[j];
    const float4* wrow = (const float4*)&Wb[(size_t)j * 512];
    const float4* hv4 = (const float4*)h_s;
#pragma unroll 2
    for (int k4 = 0; k4 < 128; k4 += 8) {
        float4 w0 = wrow[k4 + 0], w1 = wrow[k4 + 1], w2 = wrow[k4 + 2], w3 = wrow[k4 + 3];
        float4 w4 = wrow[k4 + 4], w5 = wrow[k4 + 5], w6 = wrow[k4 + 6], w7 = wrow[k4 + 7];
        float4 x0 = hv4[k4 + 0], x1 = hv4[k4 + 1], x2 = hv4[k4 + 2], x3 = hv4[k4 + 3];
        float4 x4 = hv4[k4 + 4], x5 = hv4[k4 + 5], x6 = hv4[k4 + 6], x7 = hv4[k4 + 7];
        acc += w0.x * x0.x + w0.y * x0.y + w0.z * x0.z + w0.w * x0.w;
        acc += w1.x * x1.x + w1.y * x1.y + w1.z * x1.z + w1.w * x1.w;
        acc += w2.x * x2.x + w2.y * x2.y + w2.z * x2.z + w2.w * x2.w;
        acc += w3.x * x3.x + w3.y * x3.y + w3.z * x3.z + w3.w * x3.w;
        acc += w4.x * x4.x + w4.y * x4.y + w4.z * x4.z + w4.w * x4.w;
        acc += w5.x * x5.x + w5.y * x5.y + w5.z * x5.z + w5.w * x5.w;
        acc += w6.x * x6.x + w6.y * x6.y + w6.z * x6.z + w6.w * x6.w;
        acc += w7.x * x7.x + w7.y * x7.y + w7.z * x7.z + w7.w * x7.w;
    }
    gh[b * 512 + j] = h_s[j] * sigf(acc);
}

// ---------------------------------------------------------------------------
// K6: logits GEMM.  out[b, t, n] = sum_k gh[b,k]*W_fc[n,k] + b_fc[n]
// M=128, N=12000, K=512.  250 blocks x NT=48, 256 thr, 8x3/thread
// ---------------------------------------------------------------------------
__global__ __launch_bounds__(256) void k_logits(const float* __restrict__ gh,
                                                const float* __restrict__ W_fc,
                                                const float* __restrict__ b_fc,
                                                float* __restrict__ out,
                                                int t) {
    __shared__ __align__(16) float As[16][128];
    __shared__ __align__(16) float Bs[16][52];
    const int n0 = blockIdx.x * 48;
    const int tid = threadIdx.x;
    const int ng = tid & 15, mg = tid >> 4;
    float acc[8][3];
#pragma unroll
    for (int i = 0; i < 8; i++)
#pragma unroll
        for (int j = 0; j < 3; j++) acc[i][j] = 0.f;

    for (int k0 = 0; k0 < 512; k0 += 16) {
#pragma unroll
        for (int q = 0; q < 2; q++) {
            int f = tid * 2 + q;
            int m = f >> 2, kc = (f & 3) * 4;
            float4 v = *(const float4*)&gh[(size_t)m * 512 + k0 + kc];
            As[kc + 0][m] = v.x; As[kc + 1][m] = v.y; As[kc + 2][m] = v.z; As[kc + 3][m] = v.w;
        }
        if (tid < 192) {
            int n = tid >> 2, kc = (tid & 3) * 4;
            float4 v = *(const float4*)&W_fc[(size_t)(n0 + n) * 512 + k0 + kc];
            Bs[kc + 0][n] = v.x; Bs[kc + 1][n] = v.y; Bs[kc + 2][n] = v.z; Bs[kc + 3][n] = v.w;
        }
        __syncthreads();
#pragma unroll
        for (int kk = 0; kk < 16; kk++) {
            float4 a0 = *(const float4*)&As[kk][mg * 8];
            float4 a1 = *(const float4*)&As[kk][mg * 8 + 4];
            float b0 = Bs[kk][ng * 3 + 0];
            float b1 = Bs[kk][ng * 3 + 1];
            float b2 = Bs[kk][ng * 3 + 2];
            float am[8] = {a0.x, a0.y, a0.z, a0.w, a1.x, a1.y, a1.z, a1.w};
#pragma unroll
            for (int i = 0; i < 8; i++) {
                acc[i][0] = fmaf(am[i], b0, acc[i][0]);
                acc[i][1] = fmaf(am[i], b1, acc[i][1]);
                acc[i][2] = fmaf(am[i], b2, acc[i][2]);
            }
        }
        __syncthreads();
    }
#pragma unroll
    for (int i = 0; i < 8; i++) {
        int m = mg * 8 + i;
#pragma unroll
        for (int j = 0; j < 3; j++) {
            int n = n0 + ng * 3 + j;
            out[(size_t)m * (Tv * Vv) + (size_t)t * Vv + n] = acc[i][j] + b_fc[n];
        }
    }
}

// ---------------------------------------------------------------------------
extern "C" void kernel_launch(void* const* d_in, const int* in_sizes, int n_in,
                              void* d_out, int out_size, void* d_ws, size_t ws_size,
                              hipStream_t stream) {
    const float* enc = (const float*)d_in[0];
    const int* caps = (const int*)d_in[1];
    const float* embt = (const float*)d_in[2];
    const float* We = (const float*)d_in[3];
    const float* bea = (const float*)d_in[4];
    const float* Wd = (const float*)d_in[5];
    const float* bd = (const float*)d_in[6];
    const float* Wf = (const float*)d_in[7];
    // d_in[8] = bf_att: constant across p, cancels in softmax
    const float* Wih = (const float*)d_in[9];
    const float* bih = (const float*)d_in[10];
    const float* Whh = (const float*)d_in[11];
    const float* bhh = (const float*)d_in[12];
    const float* Wb = (const float*)d_in[13];
    const float* bb = (const float*)d_in[14];
    const float* Wfc = (const float*)d_in[15];
    const float* bfc = (const float*)d_in[16];

    float* out = (float*)d_out;
    float* alpha_out = out + (size_t)Bv * Tv * Vv;

    float* ws = (float*)d_ws;
    float* att1 = ws;                        // 12,845,056 floats
    float* hbuf = att1 + (size_t)Bv * Pv * Ev;  // 65536
    float* cbuf = hbuf + Bv * Hv;            // 65536
    float* ctx = cbuf + Bv * Hv;             // 65536
    float* gh = ctx + Bv * Ev;               // 65536
    float* parts = gh + Bv * Ev;             // 8*128*2048 = 2,097,152

    // zero h and c (they are adjacent)
    hipMemsetAsync(hbuf, 0, (size_t)2 * Bv * Hv * sizeof(float), stream);

    dim3 g0(196, 8);
    k_att1<<<g0, 256, 0, stream>>>(enc, We, bea, att1);

    for (int t = 0; t < Tv; t++) {
        k_attn<<<128, 512, 0, stream>>>(att1, enc, hbuf, Wd, bd, Wf, ctx, alpha_out, t);
        dim3 g3(32, 8);
        k_gates<<<g3, 256, 0, stream>>>(embt, caps, ctx, hbuf, Wih, Whh, parts, t);
        k_lstm<<<128, 512, 0, stream>>>(parts, bih, bhh, Wb, bb, hbuf, cbuf, gh);
        k_logits<<<250, 256, 0, stream>>>(gh, Wfc, bfc, out, t);
    }
}

// Round 4
// 3034.639 us; speedup vs baseline: 1.2840x; 1.2840x over previous
//
#include <hip/hip_runtime.h>
#include <math.h>

#define Bv 128
#define Pv 196
#define Ev 512
#define Hv 512
#define Vv 12000
#define Tv 20

typedef unsigned short u16;
typedef unsigned int u32;
typedef short bf16x8 __attribute__((ext_vector_type(8)));
typedef float f32x4 __attribute__((ext_vector_type(4)));

__device__ __forceinline__ float sigf(float x) { return 1.0f / (1.0f + __expf(-x)); }
__device__ __forceinline__ u16 f2bf(float f) {
    u32 x = __float_as_uint(f);
    return (u16)((x + 0x7FFFu + ((x >> 16) & 1u)) >> 16);   // RNE
}
__device__ __forceinline__ u32 pack2(float a, float b) {
    return (u32)f2bf(a) | ((u32)f2bf(b) << 16);
}
__device__ __forceinline__ float bfl(u32 u) { return __uint_as_float(u << 16); }
__device__ __forceinline__ float bfh(u32 u) { return __uint_as_float(u & 0xFFFF0000u); }
__device__ __forceinline__ float bf2f(u16 u) { return __uint_as_float(((u32)u) << 16); }

// ---------------------------------------------------------------------------
// one-time: fp32 -> bf16 conversion (n multiple of 4)
// ---------------------------------------------------------------------------
__global__ __launch_bounds__(256) void k_cvt(const float* __restrict__ src,
                                             u16* __restrict__ dst, int n4) {
    for (int i = blockIdx.x * 256 + threadIdx.x; i < n4; i += gridDim.x * 256) {
        float4 v = ((const float4*)src)[i];
        uint2 o;
        o.x = pack2(v.x, v.y);
        o.y = pack2(v.z, v.w);
        ((uint2*)dst)[i] = o;
    }
}

// ---------------------------------------------------------------------------
// MFMA GEMM geometry (shared): BLK 128m x 64n x 64k, 256 thr = 4 waves (2x2),
// wave tile 64m x 32n = acc[4][2] of f32x4.  16x16x32 bf16 MFMA.
// A,B LDS rows padded to 72 bf16 (144B stride, 16B-aligned).
// Frag layout: A/B lane l elem j -> row (l&15), k = (l>>4)*8 + j.
// C/D: row = (l>>4)*4 + reg, col = l&15.   [m89/m91 verified mapping]
// ---------------------------------------------------------------------------

// att1[m,a] = sum_e enc[m,e]*We[a,e] + be[a]; M=25088 N=512 K=512; out bf16
__global__ __launch_bounds__(256) void k_att1_mfma(const u16* __restrict__ A,
                                                   const u16* __restrict__ Bw,
                                                   const float* __restrict__ bias,
                                                   u16* __restrict__ C) {
    __shared__ u16 As[128][72];
    __shared__ u16 Bs[64][72];
    const int n0 = blockIdx.x * 64;     // 8
    const int m0 = blockIdx.y * 128;    // 196
    const int tid = threadIdx.x;
    const int lane = tid & 63, wid = tid >> 6;
    const int wm = wid >> 1, wn = wid & 1;
    f32x4 acc[4][2] = {};
    for (int kt = 0; kt < 8; kt++) {
#pragma unroll
        for (int p = 0; p < 4; p++) {
            int flat = p * 256 + tid, row = flat >> 3, ch = flat & 7;
            uint4 v = *(const uint4*)&A[(size_t)(m0 + row) * 512 + kt * 64 + ch * 8];
            *(uint4*)&As[row][ch * 8] = v;
        }
#pragma unroll
        for (int p = 0; p < 2; p++) {
            int flat = p * 256 + tid, row = flat >> 3, ch = flat & 7;
            uint4 v = *(const uint4*)&Bw[(size_t)(n0 + row) * 512 + kt * 64 + ch * 8];
            *(uint4*)&Bs[row][ch * 8] = v;
        }
        __syncthreads();
#pragma unroll
        for (int ks = 0; ks < 2; ks++) {
            int kk = ks * 32 + (lane >> 4) * 8;
            bf16x8 af[4], bfr[2];
#pragma unroll
            for (int mf = 0; mf < 4; mf++) af[mf] = *(const bf16x8*)&As[wm * 64 + mf * 16 + (lane & 15)][kk];
#pragma unroll
            for (int nf = 0; nf < 2; nf++) bfr[nf] = *(const bf16x8*)&Bs[wn * 32 + nf * 16 + (lane & 15)][kk];
#pragma unroll
            for (int mf = 0; mf < 4; mf++)
#pragma unroll
                for (int nf = 0; nf < 2; nf++)
                    acc[mf][nf] = __builtin_amdgcn_mfma_f32_16x16x32_bf16(af[mf], bfr[nf], acc[mf][nf], 0, 0, 0);
        }
        __syncthreads();
    }
#pragma unroll
    for (int mf = 0; mf < 4; mf++)
#pragma unroll
        for (int nf = 0; nf < 2; nf++)
#pragma unroll
            for (int r = 0; r < 4; r++) {
                int m = m0 + wm * 64 + mf * 16 + (lane >> 4) * 4 + r;
                int n = n0 + wn * 32 + nf * 16 + (lane & 15);
                C[(size_t)m * 512 + n] = f2bf(acc[mf][nf][r] + bias[n]);
            }
}

// gates[b,n] over virtual K=1536: [emb(fp32,gather) | ctx(bf16) | h(fp32)]
// vs [W_ih | W_hh] (bf16).  M=128, N=2048 (32 blocks), K=24 tiles.  out fp32.
__global__ __launch_bounds__(256) void k_gates_mfma(const float* __restrict__ embt,
                                                    const int* __restrict__ caps,
                                                    const u16* __restrict__ ctxb,
                                                    const float* __restrict__ h,
                                                    const u16* __restrict__ Wihb,
                                                    const u16* __restrict__ Whhb,
                                                    float* __restrict__ gates,
                                                    int t) {
    __shared__ u16 As[128][72];
    __shared__ u16 Bs[64][72];
    const int n0 = blockIdx.x * 64;
    const int tid = threadIdx.x;
    const int lane = tid & 63, wid = tid >> 6;
    const int wm = wid >> 1, wn = wid & 1;
    f32x4 acc[4][2] = {};
    for (int kt = 0; kt < 24; kt++) {
#pragma unroll
        for (int p = 0; p < 4; p++) {
            int flat = p * 256 + tid, row = flat >> 3, ch = flat & 7;
            uint4 v;
            if (kt < 8) {
                int cap = caps[row * Tv + t];
                const float4* s = (const float4*)&embt[(size_t)cap * 512 + kt * 64 + ch * 8];
                float4 f0 = s[0], f1 = s[1];
                v.x = pack2(f0.x, f0.y); v.y = pack2(f0.z, f0.w);
                v.z = pack2(f1.x, f1.y); v.w = pack2(f1.z, f1.w);
            } else if (kt < 16) {
                v = *(const uint4*)&ctxb[(size_t)row * 512 + (kt - 8) * 64 + ch * 8];
            } else {
                const float4* s = (const float4*)&h[(size_t)row * 512 + (kt - 16) * 64 + ch * 8];
                float4 f0 = s[0], f1 = s[1];
                v.x = pack2(f0.x, f0.y); v.y = pack2(f0.z, f0.w);
                v.z = pack2(f1.x, f1.y); v.w = pack2(f1.z, f1.w);
            }
            *(uint4*)&As[row][ch * 8] = v;
        }
#pragma unroll
        for (int p = 0; p < 2; p++) {
            int flat = p * 256 + tid, row = flat >> 3, ch = flat & 7;
            uint4 v;
            if (kt < 16) v = *(const uint4*)&Wihb[(size_t)(n0 + row) * 1024 + kt * 64 + ch * 8];
            else         v = *(const uint4*)&Whhb[(size_t)(n0 + row) * 512 + (kt - 16) * 64 + ch * 8];
            *(uint4*)&Bs[row][ch * 8] = v;
        }
        __syncthreads();
#pragma unroll
        for (int ks = 0; ks < 2; ks++) {
            int kk = ks * 32 + (lane >> 4) * 8;
            bf16x8 af[4], bfr[2];
#pragma unroll
            for (int mf = 0; mf < 4; mf++) af[mf] = *(const bf16x8*)&As[wm * 64 + mf * 16 + (lane & 15)][kk];
#pragma unroll
            for (int nf = 0; nf < 2; nf++) bfr[nf] = *(const bf16x8*)&Bs[wn * 32 + nf * 16 + (lane & 15)][kk];
#pragma unroll
            for (int mf = 0; mf < 4; mf++)
#pragma unroll
                for (int nf = 0; nf < 2; nf++)
                    acc[mf][nf] = __builtin_amdgcn_mfma_f32_16x16x32_bf16(af[mf], bfr[nf], acc[mf][nf], 0, 0, 0);
        }
        __syncthreads();
    }
#pragma unroll
    for (int mf = 0; mf < 4; mf++)
#pragma unroll
        for (int nf = 0; nf < 2; nf++)
#pragma unroll
            for (int r = 0; r < 4; r++) {
                int m = wm * 64 + mf * 16 + (lane >> 4) * 4 + r;
                int n = n0 + wn * 32 + nf * 16 + (lane & 15);
                gates[(size_t)m * 2048 + n] = acc[mf][nf][r];
            }
}

// out[b,t,n] = sum_k gh[b,k]*W_fc[n,k] + b_fc[n]; M=128 N=12000 K=512
// W_fc is fp32, converted to bf16 in-register during staging (saves 11.7MB ws)
__global__ __launch_bounds__(256) void k_logits_mfma(const u16* __restrict__ A,
                                                     const float* __restrict__ Wfc,
                                                     const float* __restrict__ bias,
                                                     float* __restrict__ out,
                                                     int t) {
    __shared__ u16 As[128][72];
    __shared__ u16 Bs[64][72];
    const int n0 = blockIdx.x * 64;   // 188 blocks
    const int tid = threadIdx.x;
    const int lane = tid & 63, wid = tid >> 6;
    const int wm = wid >> 1, wn = wid & 1;
    f32x4 acc[4][2] = {};
    for (int kt = 0; kt < 8; kt++) {
#pragma unroll
        for (int p = 0; p < 4; p++) {
            int flat = p * 256 + tid, row = flat >> 3, ch = flat & 7;
            uint4 v = *(const uint4*)&A[(size_t)row * 512 + kt * 64 + ch * 8];
            *(uint4*)&As[row][ch * 8] = v;
        }
#pragma unroll
        for (int p = 0; p < 2; p++) {
            int flat = p * 256 + tid, row = flat >> 3, ch = flat & 7;
            uint4 v = {0u, 0u, 0u, 0u};
            if (n0 + row < Vv) {
                const float4* s = (const float4*)&Wfc[(size_t)(n0 + row) * 512 + kt * 64 + ch * 8];
                float4 f0 = s[0], f1 = s[1];
                v.x = pack2(f0.x, f0.y); v.y = pack2(f0.z, f0.w);
                v.z = pack2(f1.x, f1.y); v.w = pack2(f1.z, f1.w);
            }
            *(uint4*)&Bs[row][ch * 8] = v;
        }
        __syncthreads();
#pragma unroll
        for (int ks = 0; ks < 2; ks++) {
            int kk = ks * 32 + (lane >> 4) * 8;
            bf16x8 af[4], bfr[2];
#pragma unroll
            for (int mf = 0; mf < 4; mf++) af[mf] = *(const bf16x8*)&As[wm * 64 + mf * 16 + (lane & 15)][kk];
#pragma unroll
            for (int nf = 0; nf < 2; nf++) bfr[nf] = *(const bf16x8*)&Bs[wn * 32 + nf * 16 + (lane & 15)][kk];
#pragma unroll
            for (int mf = 0; mf < 4; mf++)
#pragma unroll
                for (int nf = 0; nf < 2; nf++)
                    acc[mf][nf] = __builtin_amdgcn_mfma_f32_16x16x32_bf16(af[mf], bfr[nf], acc[mf][nf], 0, 0, 0);
        }
        __syncthreads();
    }
#pragma unroll
    for (int mf = 0; mf < 4; mf++)
#pragma unroll
        for (int nf = 0; nf < 2; nf++)
#pragma unroll
            for (int r = 0; r < 4; r++) {
                int m = wm * 64 + mf * 16 + (lane >> 4) * 4 + r;
                int n = n0 + wn * 32 + nf * 16 + (lane & 15);
                if (n < Vv)
                    out[(size_t)m * (Tv * Vv) + (size_t)t * Vv + n] = acc[mf][nf][r] + bias[n];
            }
}

// ---------------------------------------------------------------------------
// per-b attention (bf16 att1/enc/Wd): att2 GEMV + e + softmax + ctx
// ---------------------------------------------------------------------------
__global__ __launch_bounds__(512) void k_attn(const u16* __restrict__ att1b,
                                              const u16* __restrict__ encb,
                                              const float* __restrict__ h,
                                              const u16* __restrict__ Wdb,
                                              const float* __restrict__ bd,
                                              const float* __restrict__ Wf,
                                              u16* __restrict__ ctxb,
                                              float* __restrict__ alpha_out,
                                              int t) {
    __shared__ float h_s[512];
    __shared__ float att2_s[512];
    __shared__ float e_s[200];
    __shared__ float alpha_s[200];
    const int b = blockIdx.x;
    const int tid = threadIdx.x;

    h_s[tid] = h[b * 512 + tid];
    __syncthreads();

    {   // att2[tid] = dot(Wd[tid,:], h) + bd
        float acc = bd[tid];
        const uint4* wrow = (const uint4*)&Wdb[(size_t)tid * 512];
        const float4* hv4 = (const float4*)h_s;
#pragma unroll 4
        for (int i = 0; i < 64; i++) {
            uint4 w = wrow[i];
            float4 x0 = hv4[2 * i], x1 = hv4[2 * i + 1];
            acc += bfl(w.x) * x0.x + bfh(w.x) * x0.y + bfl(w.y) * x0.z + bfh(w.y) * x0.w
                 + bfl(w.z) * x1.x + bfh(w.z) * x1.y + bfl(w.w) * x1.z + bfh(w.w) * x1.w;
        }
        att2_s[tid] = acc;
    }
    __syncthreads();

    const int lane = tid & 63;
    const int wv = tid >> 6;
    float att2r[8], wfr[8];
#pragma unroll
    for (int j = 0; j < 8; j++) {
        att2r[j] = att2_s[lane * 8 + j];
        wfr[j] = Wf[lane * 8 + j];
    }
    for (int p = wv; p < 196; p += 8) {
        uint4 q = *(const uint4*)&att1b[((size_t)(b * 196 + p)) * 512 + lane * 8];
        float s = wfr[0] * fmaxf(bfl(q.x) + att2r[0], 0.f) + wfr[1] * fmaxf(bfh(q.x) + att2r[1], 0.f)
                + wfr[2] * fmaxf(bfl(q.y) + att2r[2], 0.f) + wfr[3] * fmaxf(bfh(q.y) + att2r[3], 0.f)
                + wfr[4] * fmaxf(bfl(q.z) + att2r[4], 0.f) + wfr[5] * fmaxf(bfh(q.z) + att2r[5], 0.f)
                + wfr[6] * fmaxf(bfl(q.w) + att2r[6], 0.f) + wfr[7] * fmaxf(bfh(q.w) + att2r[7], 0.f);
#pragma unroll
        for (int off = 32; off; off >>= 1) s += __shfl_xor(s, off);
        if (lane == 0) e_s[p] = s;
    }
    __syncthreads();

    if (wv == 0) {
        float v0 = e_s[lane], v1 = e_s[lane + 64], v2 = e_s[lane + 128];
        float v3 = (lane < 4) ? e_s[lane + 192] : -1e30f;
        float mx = fmaxf(fmaxf(v0, v1), fmaxf(v2, v3));
#pragma unroll
        for (int off = 32; off; off >>= 1) mx = fmaxf(mx, __shfl_xor(mx, off));
        float x0 = __expf(v0 - mx), x1 = __expf(v1 - mx), x2 = __expf(v2 - mx);
        float x3 = (lane < 4) ? __expf(v3 - mx) : 0.f;
        float sm = x0 + x1 + x2 + x3;
#pragma unroll
        for (int off = 32; off; off >>= 1) sm += __shfl_xor(sm, off);
        float inv = 1.0f / sm;
        x0 *= inv; x1 *= inv; x2 *= inv; x3 *= inv;
        alpha_s[lane] = x0; alpha_s[lane + 64] = x1; alpha_s[lane + 128] = x2;
        if (lane < 4) alpha_s[lane + 192] = x3;
        float* ao = alpha_out + ((size_t)b * Tv + t) * 196;
        ao[lane] = x0; ao[lane + 64] = x1; ao[lane + 128] = x2;
        if (lane < 4) ao[lane + 192] = x3;
    }
    __syncthreads();

    {   // ctx[tid] = sum_p alpha[p]*enc[b,p,tid]
        float acc = 0.f;
        const u16* ecol = &encb[(size_t)b * 196 * 512 + tid];
#pragma unroll 4
        for (int p = 0; p < 196; p++) acc += alpha_s[p] * bf2f(ecol[(size_t)p * 512]);
        ctxb[b * 512 + tid] = f2bf(acc);
    }
}

// ---------------------------------------------------------------------------
// LSTM pointwise (+biases) + beta-gate GEMV; writes h,c fp32 and gh bf16
// ---------------------------------------------------------------------------
__global__ __launch_bounds__(512) void k_lstm(const float* __restrict__ gates,
                                              const float* __restrict__ b_ih,
                                              const float* __restrict__ b_hh,
                                              const u16* __restrict__ Wbb,
                                              const float* __restrict__ bb,
                                              float* __restrict__ h,
                                              float* __restrict__ c,
                                              u16* __restrict__ ghb) {
    __shared__ float h_s[512];
    const int b = blockIdx.x;
    const int j = threadIdx.x;
    const float* gr = &gates[(size_t)b * 2048];
    float gi = b_ih[j] + b_hh[j] + gr[j];
    float gf = b_ih[j + 512] + b_hh[j + 512] + gr[j + 512];
    float gg = b_ih[j + 1024] + b_hh[j + 1024] + gr[j + 1024];
    float go = b_ih[j + 1536] + b_hh[j + 1536] + gr[j + 1536];
    float cn = sigf(gf) * c[b * 512 + j] + sigf(gi) * tanhf(gg);
    float hn = sigf(go) * tanhf(cn);
    c[b * 512 + j] = cn;
    h[b * 512 + j] = hn;
    h_s[j] = hn;
    __syncthreads();

    float acc = bb[j];
    const uint4* wrow = (const uint4*)&Wbb[(size_t)j * 512];
    const float4* hv4 = (const float4*)h_s;
#pragma unroll 4
    for (int i = 0; i < 64; i++) {
        uint4 w = wrow[i];
        float4 x0 = hv4[2 * i], x1 = hv4[2 * i + 1];
        acc += bfl(w.x) * x0.x + bfh(w.x) * x0.y + bfl(w.y) * x0.z + bfh(w.y) * x0.w
             + bfl(w.z) * x1.x + bfh(w.z) * x1.y + bfl(w.w) * x1.z + bfh(w.w) * x1.w;
    }
    ghb[b * 512 + j] = f2bf(hn * sigf(acc));
}

// ---------------------------------------------------------------------------
extern "C" void kernel_launch(void* const* d_in, const int* in_sizes, int n_in,
                              void* d_out, int out_size, void* d_ws, size_t ws_size,
                              hipStream_t stream) {
    const float* enc = (const float*)d_in[0];
    const int* caps = (const int*)d_in[1];
    const float* embt = (const float*)d_in[2];
    const float* We = (const float*)d_in[3];
    const float* bea = (const float*)d_in[4];
    const float* Wd = (const float*)d_in[5];
    const float* bd = (const float*)d_in[6];
    const float* Wf = (const float*)d_in[7];
    // d_in[8] = bf_att: constant across p, cancels in softmax
    const float* Wih = (const float*)d_in[9];
    const float* bih = (const float*)d_in[10];
    const float* Whh = (const float*)d_in[11];
    const float* bhh = (const float*)d_in[12];
    const float* Wb = (const float*)d_in[13];
    const float* bb = (const float*)d_in[14];
    const float* Wfc = (const float*)d_in[15];
    const float* bfc = (const float*)d_in[16];

    float* out = (float*)d_out;
    float* alpha_out = out + (size_t)Bv * Tv * Vv;

    // workspace layout — total ~61.1 MB (matches R2's proven footprint)
    u16* encb = (u16*)d_ws;                       // 12,845,056
    u16* att1b = encb + (size_t)12845056;         // 12,845,056
    u16* Wihb = att1b + (size_t)12845056;         // 2,097,152
    u16* Whhb = Wihb + 2097152;                   // 1,048,576
    u16* Web = Whhb + 1048576;                    // 262,144
    u16* Wdb = Web + 262144;                      // 262,144
    u16* Wbb = Wdb + 262144;                      // 262,144
    u16* ctxb = Wbb + 262144;                     // 65,536
    u16* ghb = ctxb + 65536;                      // 65,536
    float* gates = (float*)(ghb + 65536);         // 262,144 f32
    float* hbuf = gates + 262144;                 // 65,536
    float* cbuf = hbuf + 65536;                   // 65,536

    hipMemsetAsync(hbuf, 0, (size_t)2 * Bv * Hv * sizeof(float), stream);

    // one-time conversions
    k_cvt<<<1024, 256, 0, stream>>>(enc, encb, 12845056 / 4);
    k_cvt<<<512, 256, 0, stream>>>(Wih, Wihb, 2097152 / 4);
    k_cvt<<<256, 256, 0, stream>>>(Whh, Whhb, 1048576 / 4);
    k_cvt<<<64, 256, 0, stream>>>(We, Web, 262144 / 4);
    k_cvt<<<64, 256, 0, stream>>>(Wd, Wdb, 262144 / 4);
    k_cvt<<<64, 256, 0, stream>>>(Wb, Wbb, 262144 / 4);

    dim3 g0(8, 196);   // n fast-varying: consecutive blocks share the A m-tile
    k_att1_mfma<<<g0, 256, 0, stream>>>(encb, Web, bea, att1b);

    for (int t = 0; t < Tv; t++) {
        k_attn<<<128, 512, 0, stream>>>(att1b, encb, hbuf, Wdb, bd, Wf, ctxb, alpha_out, t);
        k_gates_mfma<<<32, 256, 0, stream>>>(embt, caps, ctxb, hbuf, Wihb, Whhb, gates, t);
        k_lstm<<<128, 512, 0, stream>>>(gates, bih, bhh, Wbb, bb, hbuf, cbuf, ghb);
        k_logits_mfma<<<188, 256, 0, stream>>>(ghb, Wfc, bfc, out, t);
    }
}

// Round 5
// 1904.787 us; speedup vs baseline: 2.0457x; 1.5932x over previous
//
#include <hip/hip_runtime.h>
#include <math.h>

#define Bv 128
#define Pv 196
#define Ev 512
#define Hv 512
#define Vv 12000
#define Tv 20

typedef unsigned short u16;
typedef unsigned int u32;
typedef short bf16x8 __attribute__((ext_vector_type(8)));
typedef float f32x4 __attribute__((ext_vector_type(4)));

__device__ __forceinline__ float sigf(float x) { return 1.0f / (1.0f + __expf(-x)); }
__device__ __forceinline__ u16 f2bf(float f) {
    u32 x = __float_as_uint(f);
    return (u16)((x + 0x7FFFu + ((x >> 16) & 1u)) >> 16);   // RNE
}
__device__ __forceinline__ u32 pack2(float a, float b) {
    return (u32)f2bf(a) | ((u32)f2bf(b) << 16);
}
__device__ __forceinline__ float bfl(u32 u) { return __uint_as_float(u << 16); }
__device__ __forceinline__ float bfh(u32 u) { return __uint_as_float(u & 0xFFFF0000u); }
__device__ __forceinline__ float bf2f(u16 u) { return __uint_as_float(((u32)u) << 16); }

// ---------------------------------------------------------------------------
__global__ __launch_bounds__(256) void k_cvt(const float* __restrict__ src,
                                             u16* __restrict__ dst, int n4) {
    for (int i = blockIdx.x * 256 + threadIdx.x; i < n4; i += gridDim.x * 256) {
        float4 v = ((const float4*)src)[i];
        uint2 o;
        o.x = pack2(v.x, v.y);
        o.y = pack2(v.z, v.w);
        ((uint2*)dst)[i] = o;
    }
}

// ---------------------------------------------------------------------------
// MFMA template: BLK 128m x 64n x 64k, 256 thr = 4 waves (2x2),
// wave tile 64m x 32n = acc[4][2] f32x4.  16x16x32 bf16 MFMA.
// LDS rows padded to 72 bf16.  A/B frag: lane l elem j -> row (l&15),
// k = (l>>4)*8 + j.  C/D: row = (l>>4)*4 + reg, col = l&15.
// ---------------------------------------------------------------------------

// att1 = enc @ We^T + be; M=25088 N=512 K=512; out bf16
__global__ __launch_bounds__(256) void k_att1_mfma(const u16* __restrict__ A,
                                                   const u16* __restrict__ Bw,
                                                   const float* __restrict__ bias,
                                                   u16* __restrict__ C) {
    __shared__ u16 As[128][72];
    __shared__ u16 Bs[64][72];
    const int n0 = blockIdx.x * 64;
    const int m0 = blockIdx.y * 128;
    const int tid = threadIdx.x;
    const int lane = tid & 63, wid = tid >> 6;
    const int wm = wid >> 1, wn = wid & 1;
    f32x4 acc[4][2] = {};
    for (int kt = 0; kt < 8; kt++) {
#pragma unroll
        for (int p = 0; p < 4; p++) {
            int flat = p * 256 + tid, row = flat >> 3, ch = flat & 7;
            *(uint4*)&As[row][ch * 8] = *(const uint4*)&A[(size_t)(m0 + row) * 512 + kt * 64 + ch * 8];
        }
#pragma unroll
        for (int p = 0; p < 2; p++) {
            int flat = p * 256 + tid, row = flat >> 3, ch = flat & 7;
            *(uint4*)&Bs[row][ch * 8] = *(const uint4*)&Bw[(size_t)(n0 + row) * 512 + kt * 64 + ch * 8];
        }
        __syncthreads();
#pragma unroll
        for (int ks = 0; ks < 2; ks++) {
            int kk = ks * 32 + (lane >> 4) * 8;
            bf16x8 af[4], bfr[2];
#pragma unroll
            for (int mf = 0; mf < 4; mf++) af[mf] = *(const bf16x8*)&As[wm * 64 + mf * 16 + (lane & 15)][kk];
#pragma unroll
            for (int nf = 0; nf < 2; nf++) bfr[nf] = *(const bf16x8*)&Bs[wn * 32 + nf * 16 + (lane & 15)][kk];
#pragma unroll
            for (int mf = 0; mf < 4; mf++)
#pragma unroll
                for (int nf = 0; nf < 2; nf++)
                    acc[mf][nf] = __builtin_amdgcn_mfma_f32_16x16x32_bf16(af[mf], bfr[nf], acc[mf][nf], 0, 0, 0);
        }
        __syncthreads();
    }
#pragma unroll
    for (int mf = 0; mf < 4; mf++)
#pragma unroll
        for (int nf = 0; nf < 2; nf++)
#pragma unroll
            for (int r = 0; r < 4; r++) {
                int m = m0 + wm * 64 + mf * 16 + (lane >> 4) * 4 + r;
                int n = n0 + wn * 32 + nf * 16 + (lane & 15);
                C[(size_t)m * 512 + n] = f2bf(acc[mf][nf][r] + bias[n]);
            }
}

// ---------------------------------------------------------------------------
// per-b attention.  h read as bf16 from hall slot t (= h_{t-1}).
// ---------------------------------------------------------------------------
__global__ __launch_bounds__(512) void k_attn(const u16* __restrict__ att1b,
                                              const u16* __restrict__ encb,
                                              const u16* __restrict__ hprev,
                                              const u16* __restrict__ Wdb,
                                              const float* __restrict__ bd,
                                              const float* __restrict__ Wf,
                                              u16* __restrict__ ctxb,
                                              float* __restrict__ alpha_out,
                                              int t) {
    __shared__ float h_s[512];
    __shared__ float att2_s[512];
    __shared__ float e_s[200];
    __shared__ float alpha_s[200];
    const int b = blockIdx.x;
    const int tid = threadIdx.x;

    h_s[tid] = bf2f(hprev[b * 512 + tid]);
    __syncthreads();

    {   // att2[tid] = dot(Wd[tid,:], h) + bd
        float acc = bd[tid];
        const uint4* wrow = (const uint4*)&Wdb[(size_t)tid * 512];
        const float4* hv4 = (const float4*)h_s;
#pragma unroll 4
        for (int i = 0; i < 64; i++) {
            uint4 w = wrow[i];
            float4 x0 = hv4[2 * i], x1 = hv4[2 * i + 1];
            acc += bfl(w.x) * x0.x + bfh(w.x) * x0.y + bfl(w.y) * x0.z + bfh(w.y) * x0.w
                 + bfl(w.z) * x1.x + bfh(w.z) * x1.y + bfl(w.w) * x1.z + bfh(w.w) * x1.w;
        }
        att2_s[tid] = acc;
    }
    __syncthreads();

    const int lane = tid & 63;
    const int wv = tid >> 6;
    float att2r[8], wfr[8];
#pragma unroll
    for (int j = 0; j < 8; j++) {
        att2r[j] = att2_s[lane * 8 + j];
        wfr[j] = Wf[lane * 8 + j];
    }
    for (int p = wv; p < 196; p += 8) {
        uint4 q = *(const uint4*)&att1b[((size_t)(b * 196 + p)) * 512 + lane * 8];
        float s = wfr[0] * fmaxf(bfl(q.x) + att2r[0], 0.f) + wfr[1] * fmaxf(bfh(q.x) + att2r[1], 0.f)
                + wfr[2] * fmaxf(bfl(q.y) + att2r[2], 0.f) + wfr[3] * fmaxf(bfh(q.y) + att2r[3], 0.f)
                + wfr[4] * fmaxf(bfl(q.z) + att2r[4], 0.f) + wfr[5] * fmaxf(bfh(q.z) + att2r[5], 0.f)
                + wfr[6] * fmaxf(bfl(q.w) + att2r[6], 0.f) + wfr[7] * fmaxf(bfh(q.w) + att2r[7], 0.f);
#pragma unroll
        for (int off = 32; off; off >>= 1) s += __shfl_xor(s, off);
        if (lane == 0) e_s[p] = s;
    }
    __syncthreads();

    if (wv == 0) {
        float v0 = e_s[lane], v1 = e_s[lane + 64], v2 = e_s[lane + 128];
        float v3 = (lane < 4) ? e_s[lane + 192] : -1e30f;
        float mx = fmaxf(fmaxf(v0, v1), fmaxf(v2, v3));
#pragma unroll
        for (int off = 32; off; off >>= 1) mx = fmaxf(mx, __shfl_xor(mx, off));
        float x0 = __expf(v0 - mx), x1 = __expf(v1 - mx), x2 = __expf(v2 - mx);
        float x3 = (lane < 4) ? __expf(v3 - mx) : 0.f;
        float sm = x0 + x1 + x2 + x3;
#pragma unroll
        for (int off = 32; off; off >>= 1) sm += __shfl_xor(sm, off);
        float inv = 1.0f / sm;
        x0 *= inv; x1 *= inv; x2 *= inv; x3 *= inv;
        alpha_s[lane] = x0; alpha_s[lane + 64] = x1; alpha_s[lane + 128] = x2;
        if (lane < 4) alpha_s[lane + 192] = x3;
        float* ao = alpha_out + ((size_t)b * Tv + t) * 196;
        ao[lane] = x0; ao[lane + 64] = x1; ao[lane + 128] = x2;
        if (lane < 4) ao[lane + 192] = x3;
    }
    __syncthreads();

    {   // ctx[tid] = sum_p alpha[p]*enc[b,p,tid]
        float acc = 0.f;
        const u16* ecol = &encb[(size_t)b * 196 * 512 + tid];
#pragma unroll 4
        for (int p = 0; p < 196; p++) acc += alpha_s[p] * bf2f(ecol[(size_t)p * 512]);
        ctxb[b * 512 + tid] = f2bf(acc);
    }
}

// ---------------------------------------------------------------------------
// fused gates-GEMM + LSTM pointwise.
// grid (32 j-groups, 2 m-halves) x 256 thr.  Block: M=64 (b-half),
// NT=64 = 16 j x 4 gate-quadrants (n = q*512 + jg*16 + jj), K=1536 virtual:
// [emb(fp32 gather) | ctx(bf16) | h_{t-1}(bf16 hall slot)].
// Wave (2x2): wave tile 32m x 32n = acc[2][2]; q = wn*2+nf, jj = lane&15.
// Epilogue: gates -> LDS planes -> c/h update; h written bf16 to hall slot t+1.
// ---------------------------------------------------------------------------
__global__ __launch_bounds__(256) void k_gateslstm(const float* __restrict__ embt,
                                                   const int* __restrict__ caps,
                                                   const u16* __restrict__ ctxb,
                                                   const u16* __restrict__ hprev,
                                                   const u16* __restrict__ Wihb,
                                                   const u16* __restrict__ Whhb,
                                                   const float* __restrict__ bih,
                                                   const float* __restrict__ bhh,
                                                   float* __restrict__ cbuf,
                                                   u16* __restrict__ hnext,
                                                   int t) {
    __shared__ u16 As[64][72];
    __shared__ u16 Bs[64][72];
    __shared__ float gate_lds[4][64][16];
    const int jg = blockIdx.x;           // 0..31
    const int mh = blockIdx.y;           // 0..1
    const int tid = threadIdx.x;
    const int lane = tid & 63, wid = tid >> 6;
    const int wm = wid >> 1, wn = wid & 1;
    f32x4 acc[2][2] = {};

    for (int kt = 0; kt < 24; kt++) {
#pragma unroll
        for (int p = 0; p < 2; p++) {     // A: 64 rows x 8 chunks
            int flat = p * 256 + tid, row = flat >> 3, ch = flat & 7;
            int brow = mh * 64 + row;
            uint4 v;
            if (kt < 8) {
                int cap = caps[brow * Tv + t];
                const float4* s = (const float4*)&embt[(size_t)cap * 512 + kt * 64 + ch * 8];
                float4 f0 = s[0], f1 = s[1];
                v.x = pack2(f0.x, f0.y); v.y = pack2(f0.z, f0.w);
                v.z = pack2(f1.x, f1.y); v.w = pack2(f1.z, f1.w);
            } else if (kt < 16) {
                v = *(const uint4*)&ctxb[(size_t)brow * 512 + (kt - 8) * 64 + ch * 8];
            } else {
                v = *(const uint4*)&hprev[(size_t)brow * 512 + (kt - 16) * 64 + ch * 8];
            }
            *(uint4*)&As[row][ch * 8] = v;
        }
#pragma unroll
        for (int p = 0; p < 2; p++) {     // B: 64 rows (16 j x 4 q)
            int flat = p * 256 + tid, row = flat >> 3, ch = flat & 7;
            int n = (row >> 4) * 512 + jg * 16 + (row & 15);
            uint4 v;
            if (kt < 16) v = *(const uint4*)&Wihb[(size_t)n * 1024 + kt * 64 + ch * 8];
            else         v = *(const uint4*)&Whhb[(size_t)n * 512 + (kt - 16) * 64 + ch * 8];
            *(uint4*)&Bs[row][ch * 8] = v;
        }
        __syncthreads();
#pragma unroll
        for (int ks = 0; ks < 2; ks++) {
            int kk = ks * 32 + (lane >> 4) * 8;
            bf16x8 af[2], bfr[2];
#pragma unroll
            for (int mf = 0; mf < 2; mf++) af[mf] = *(const bf16x8*)&As[wm * 32 + mf * 16 + (lane & 15)][kk];
#pragma unroll
            for (int nf = 0; nf < 2; nf++) bfr[nf] = *(const bf16x8*)&Bs[wn * 32 + nf * 16 + (lane & 15)][kk];
#pragma unroll
            for (int mf = 0; mf < 2; mf++)
#pragma unroll
                for (int nf = 0; nf < 2; nf++)
                    acc[mf][nf] = __builtin_amdgcn_mfma_f32_16x16x32_bf16(af[mf], bfr[nf], acc[mf][nf], 0, 0, 0);
        }
        __syncthreads();
    }
    // scatter gate quadrants to LDS planes
#pragma unroll
    for (int mf = 0; mf < 2; mf++)
#pragma unroll
        for (int nf = 0; nf < 2; nf++) {
            int q = wn * 2 + nf;
            int jj = lane & 15;
#pragma unroll
            for (int r = 0; r < 4; r++) {
                int m = wm * 32 + mf * 16 + (lane >> 4) * 4 + r;
                gate_lds[q][m][jj] = acc[mf][nf][r];
            }
        }
    __syncthreads();
    // LSTM pointwise: 64 m x 16 jj = 1024 elems, 4 per thread
#pragma unroll
    for (int i = 0; i < 4; i++) {
        int idx = i * 256 + tid;
        int m = idx >> 4, jj = idx & 15;
        int col = jg * 16 + jj;
        int brow = mh * 64 + m;
        float gi = gate_lds[0][m][jj] + bih[col] + bhh[col];
        float gf = gate_lds[1][m][jj] + bih[col + 512] + bhh[col + 512];
        float gg = gate_lds[2][m][jj] + bih[col + 1024] + bhh[col + 1024];
        float go = gate_lds[3][m][jj] + bih[col + 1536] + bhh[col + 1536];
        float cn = sigf(gf) * cbuf[brow * 512 + col] + sigf(gi) * tanhf(gg);
        float hn = sigf(go) * tanhf(cn);
        cbuf[brow * 512 + col] = cn;
        hnext[brow * 512 + col] = f2bf(hn);
    }
}

// ---------------------------------------------------------------------------
// batched beta gate: gh[m,n] = hall[m,n] * sig(sum_k hall[m,k]*Wb[n,k] + bb[n])
// M=2560 N=512 K=512.  grid (8, 20).
// ---------------------------------------------------------------------------
__global__ __launch_bounds__(256) void k_beta_mfma(const u16* __restrict__ hall,
                                                   const u16* __restrict__ Wbb,
                                                   const float* __restrict__ bb,
                                                   u16* __restrict__ ghall) {
    __shared__ u16 As[128][72];
    __shared__ u16 Bs[64][72];
    const int n0 = blockIdx.x * 64;
    const int m0 = blockIdx.y * 128;
    const int tid = threadIdx.x;
    const int lane = tid & 63, wid = tid >> 6;
    const int wm = wid >> 1, wn = wid & 1;
    f32x4 acc[4][2] = {};
    for (int kt = 0; kt < 8; kt++) {
#pragma unroll
        for (int p = 0; p < 4; p++) {
            int flat = p * 256 + tid, row = flat >> 3, ch = flat & 7;
            *(uint4*)&As[row][ch * 8] = *(const uint4*)&hall[(size_t)(m0 + row) * 512 + kt * 64 + ch * 8];
        }
#pragma unroll
        for (int p = 0; p < 2; p++) {
            int flat = p * 256 + tid, row = flat >> 3, ch = flat & 7;
            *(uint4*)&Bs[row][ch * 8] = *(const uint4*)&Wbb[(size_t)(n0 + row) * 512 + kt * 64 + ch * 8];
        }
        __syncthreads();
#pragma unroll
        for (int ks = 0; ks < 2; ks++) {
            int kk = ks * 32 + (lane >> 4) * 8;
            bf16x8 af[4], bfr[2];
#pragma unroll
            for (int mf = 0; mf < 4; mf++) af[mf] = *(const bf16x8*)&As[wm * 64 + mf * 16 + (lane & 15)][kk];
#pragma unroll
            for (int nf = 0; nf < 2; nf++) bfr[nf] = *(const bf16x8*)&Bs[wn * 32 + nf * 16 + (lane & 15)][kk];
#pragma unroll
            for (int mf = 0; mf < 4; mf++)
#pragma unroll
                for (int nf = 0; nf < 2; nf++)
                    acc[mf][nf] = __builtin_amdgcn_mfma_f32_16x16x32_bf16(af[mf], bfr[nf], acc[mf][nf], 0, 0, 0);
        }
        __syncthreads();
    }
#pragma unroll
    for (int mf = 0; mf < 4; mf++)
#pragma unroll
        for (int nf = 0; nf < 2; nf++)
#pragma unroll
            for (int r = 0; r < 4; r++) {
                int m = m0 + wm * 64 + mf * 16 + (lane >> 4) * 4 + r;
                int n = n0 + wn * 32 + nf * 16 + (lane & 15);
                float h = bf2f(hall[(size_t)m * 512 + n]);
                ghall[(size_t)m * 512 + n] = f2bf(h * sigf(acc[mf][nf][r] + bb[n]));
            }
}

// ---------------------------------------------------------------------------
// batched logits: out[b,t,n] = sum_k ghall[t*128+b, k]*Wfc[n,k] + bfc[n]
// M=2560 N=12000 K=512.  grid (188, 20).
// ---------------------------------------------------------------------------
__global__ __launch_bounds__(256) void k_logits_mega(const u16* __restrict__ ghall,
                                                     const u16* __restrict__ Wfcb,
                                                     const float* __restrict__ bias,
                                                     float* __restrict__ out) {
    __shared__ u16 As[128][72];
    __shared__ u16 Bs[64][72];
    const int n0 = blockIdx.x * 64;
    const int m0 = blockIdx.y * 128;
    const int tid = threadIdx.x;
    const int lane = tid & 63, wid = tid >> 6;
    const int wm = wid >> 1, wn = wid & 1;
    f32x4 acc[4][2] = {};
    for (int kt = 0; kt < 8; kt++) {
#pragma unroll
        for (int p = 0; p < 4; p++) {
            int flat = p * 256 + tid, row = flat >> 3, ch = flat & 7;
            *(uint4*)&As[row][ch * 8] = *(const uint4*)&ghall[(size_t)(m0 + row) * 512 + kt * 64 + ch * 8];
        }
#pragma unroll
        for (int p = 0; p < 2; p++) {
            int flat = p * 256 + tid, row = flat >> 3, ch = flat & 7;
            uint4 v = {0u, 0u, 0u, 0u};
            if (n0 + row < Vv)
                v = *(const uint4*)&Wfcb[(size_t)(n0 + row) * 512 + kt * 64 + ch * 8];
            *(uint4*)&Bs[row][ch * 8] = v;
        }
        __syncthreads();
#pragma unroll
        for (int ks = 0; ks < 2; ks++) {
            int kk = ks * 32 + (lane >> 4) * 8;
            bf16x8 af[4], bfr[2];
#pragma unroll
            for (int mf = 0; mf < 4; mf++) af[mf] = *(const bf16x8*)&As[wm * 64 + mf * 16 + (lane & 15)][kk];
#pragma unroll
            for (int nf = 0; nf < 2; nf++) bfr[nf] = *(const bf16x8*)&Bs[wn * 32 + nf * 16 + (lane & 15)][kk];
#pragma unroll
            for (int mf = 0; mf < 4; mf++)
#pragma unroll
                for (int nf = 0; nf < 2; nf++)
                    acc[mf][nf] = __builtin_amdgcn_mfma_f32_16x16x32_bf16(af[mf], bfr[nf], acc[mf][nf], 0, 0, 0);
        }
        __syncthreads();
    }
#pragma unroll
    for (int mf = 0; mf < 4; mf++)
#pragma unroll
        for (int nf = 0; nf < 2; nf++)
#pragma unroll
            for (int r = 0; r < 4; r++) {
                int m = m0 + wm * 64 + mf * 16 + (lane >> 4) * 4 + r;
                int n = n0 + wn * 32 + nf * 16 + (lane & 15);
                if (n < Vv) {
                    int tt = m >> 7, b = m & 127;
                    out[(size_t)b * (Tv * Vv) + (size_t)tt * Vv + n] = acc[mf][nf][r] + bias[n];
                }
            }
}

// ---------------------------------------------------------------------------
extern "C" void kernel_launch(void* const* d_in, const int* in_sizes, int n_in,
                              void* d_out, int out_size, void* d_ws, size_t ws_size,
                              hipStream_t stream) {
    const float* enc = (const float*)d_in[0];
    const int* caps = (const int*)d_in[1];
    const float* embt = (const float*)d_in[2];
    const float* We = (const float*)d_in[3];
    const float* bea = (const float*)d_in[4];
    const float* Wd = (const float*)d_in[5];
    const float* bd = (const float*)d_in[6];
    const float* Wf = (const float*)d_in[7];
    // d_in[8] = bf_att: constant across p, cancels in softmax
    const float* Wih = (const float*)d_in[9];
    const float* bih = (const float*)d_in[10];
    const float* Whh = (const float*)d_in[11];
    const float* bhh = (const float*)d_in[12];
    const float* Wb = (const float*)d_in[13];
    const float* bb = (const float*)d_in[14];
    const float* Wfc = (const float*)d_in[15];
    const float* bfc = (const float*)d_in[16];

    float* out = (float*)d_out;
    float* alpha_out = out + (size_t)Bv * Tv * Vv;

    // workspace (ws_size ~500MB per fill counter; we use ~78MB)
    u16* encb = (u16*)d_ws;                       // 12,845,056
    u16* att1b = encb + (size_t)12845056;         // 12,845,056
    u16* Wfcb = att1b + (size_t)12845056;         // 6,144,000
    u16* Wihb = Wfcb + 6144000;                   // 2,097,152
    u16* Whhb = Wihb + 2097152;                   // 1,048,576
    u16* Web = Whhb + 1048576;                    // 262,144
    u16* Wdb = Web + 262144;                      // 262,144
    u16* Wbb = Wdb + 262144;                      // 262,144
    u16* ctxb = Wbb + 262144;                     // 65,536
    u16* hall = ctxb + 65536;                     // 21*65536 (slot 0 = zeros = h_{-1})
    u16* ghall = hall + 21 * 65536;               // 20*65536
    float* cbuf = (float*)(ghall + 20 * 65536);   // 65,536 f32

    // zero h_{-1} slot and c
    hipMemsetAsync(hall, 0, 65536 * sizeof(u16), stream);
    hipMemsetAsync(cbuf, 0, 65536 * sizeof(float), stream);

    // one-time conversions
    k_cvt<<<1024, 256, 0, stream>>>(enc, encb, 12845056 / 4);
    k_cvt<<<1024, 256, 0, stream>>>(Wfc, Wfcb, 6144000 / 4);
    k_cvt<<<512, 256, 0, stream>>>(Wih, Wihb, 2097152 / 4);
    k_cvt<<<256, 256, 0, stream>>>(Whh, Whhb, 1048576 / 4);
    k_cvt<<<64, 256, 0, stream>>>(We, Web, 262144 / 4);
    k_cvt<<<64, 256, 0, stream>>>(Wd, Wdb, 262144 / 4);
    k_cvt<<<64, 256, 0, stream>>>(Wb, Wbb, 262144 / 4);

    dim3 g0(8, 196);
    k_att1_mfma<<<g0, 256, 0, stream>>>(encb, Web, bea, att1b);

    for (int t = 0; t < Tv; t++) {
        const u16* hprev = hall + (size_t)t * 65536;
        u16* hnext = hall + (size_t)(t + 1) * 65536;
        k_attn<<<128, 512, 0, stream>>>(att1b, encb, hprev, Wdb, bd, Wf, ctxb, alpha_out, t);
        dim3 gg(32, 2);
        k_gateslstm<<<gg, 256, 0, stream>>>(embt, caps, ctxb, hprev, Wihb, Whhb,
                                            bih, bhh, cbuf, hnext, t);
    }

    dim3 gb(8, 20);
    k_beta_mfma<<<gb, 256, 0, stream>>>(hall + 65536, Wbb, bb, ghall);
    dim3 gl(188, 20);
    k_logits_mega<<<gl, 256, 0, stream>>>(ghall, Wfcb, bfc, out);
}